// Round 9
// baseline (2337.308 us; speedup 1.0000x reference)
//
#include <hip/hip_runtime.h>

#define NG 20000
#define ND 8000
#define NS 8000
#define EE 300000
#define DIM 256
#define SCALE_QK 0.17677669529663687f  // 1/sqrt(32)
#define LNEPS 1e-5f

__device__ __forceinline__ float bf2f(unsigned short u) {
    union { unsigned u; float f; } c; c.u = ((unsigned)u) << 16; return c.f;
}
__device__ __forceinline__ unsigned short f2bf(float f) {
    union { float f; unsigned u; } c; c.f = f;
    return (unsigned short)((c.u + 0x7fffu + ((c.u >> 16) & 1u)) >> 16);
}
__device__ __forceinline__ float gelu_exact(float v) {
    return 0.5f * v * (1.0f + erff(v * 0.70710678118654752f));
}
// order-preserving float<->uint for atomicMax on floats
__device__ __forceinline__ unsigned ford(float f) {
    unsigned b = __float_as_uint(f);
    return (b & 0x80000000u) ? ~b : (b | 0x80000000u);
}
__device__ __forceinline__ float ford_inv(unsigned u) {
    return __uint_as_float((u & 0x80000000u) ? (u & 0x7fffffffu) : ~u);
}

// ---------------------------------------------------------------------------
// Simple VALU GEMM: C[M,256] = A[M,256] @ W[256,256]^T + bias  -> bf16 scratch
// One block per 16 rows; thread t owns output column t (= W row t).
// A: fp32 (ABF=0) or bf16 scratch (ABF=1). W,bias fp32.
// MODE 0: store bf16 C.  MODE 1: Bahdanau epilogue e[m] += sum_n v[n]*tanh(C+b)
// ---------------------------------------------------------------------------
template <int MODE, int ABF>
__global__ __launch_bounds__(256) void gemm_simple(
    const void* __restrict__ Ap, const float* __restrict__ W,
    const float* __restrict__ bias, unsigned short* __restrict__ C,
    const float* __restrict__ vvec, float* __restrict__ evec, int M)
{
    __shared__ float As[16][256];
    const int r0 = blockIdx.x * 16;
    const int t = threadIdx.x;
#pragma unroll
    for (int i = 0; i < 16; ++i) {
        int gm = r0 + i;
        float v = 0.f;
        if (gm < M) {
            if (ABF) v = bf2f(((const unsigned short*)Ap)[(size_t)gm * 256 + t]);
            else     v = ((const float*)Ap)[(size_t)gm * 256 + t];
        }
        As[i][t] = v;
    }
    __syncthreads();
    float c[16];
#pragma unroll
    for (int i = 0; i < 16; ++i) c[i] = 0.f;
    const float* wrow = W + (size_t)t * 256;
    for (int k = 0; k < 256; ++k) {
        float w = wrow[k];
#pragma unroll
        for (int i = 0; i < 16; ++i) c[i] += As[i][k] * w;
    }
    if (MODE == 0) {
        float bn = bias[t];
#pragma unroll
        for (int i = 0; i < 16; ++i) {
            int m = r0 + i;
            if (m < M) C[(size_t)m * 256 + t] = f2bf(c[i] + bn);
        }
    } else {
        int lane = t & 63;
        float vn = vvec[t], bn = bias[t];
#pragma unroll
        for (int i = 0; i < 16; ++i) {
            int m = r0 + i;
            if (m < M) {
                float s = vn * tanhf(c[i] + bn);
                s += __shfl_xor(s, 1);  s += __shfl_xor(s, 2);
                s += __shfl_xor(s, 4);  s += __shfl_xor(s, 8);
                s += __shfl_xor(s, 16); s += __shfl_xor(s, 32);
                if (lane == 0) atomicAdd(&evec[m], s);
            }
        }
    }
}

__global__ void zero_kernel(int* __restrict__ p, int n) {
    int i = blockIdx.x * blockDim.x + threadIdx.x;
    if (i < n) p[i] = 0;
}
__global__ void fillf_kernel(float* __restrict__ p, int n, float v) {
    int i = blockIdx.x * blockDim.x + threadIdx.x;
    if (i < n) p[i] = v;
}

// ---------------------------------------------------------------------------
// Edge-parallel attention (direct transcription of the reference):
// pass1: score[e,h] = (K[src]·Q[dst])_h * SCALE; atomicMax m[dst,h]
// pass2: a = exp(score - m[dst,h]); score[e,h]=a; atomicAdd denom[dst,h]
// pass3: acc[dst,f] += V[src,f] * a[e, f/32]   (fp32 atomics)
// ---------------------------------------------------------------------------
__global__ __launch_bounds__(256) void score_pass1(
    const unsigned short* __restrict__ Q, const unsigned short* __restrict__ K,
    const int* __restrict__ src, const int* __restrict__ dst,
    float* __restrict__ score, unsigned* __restrict__ m_ord)
{
    int idx = blockIdx.x * 256 + threadIdx.x;
    if (idx >= EE * 8) return;
    int e = idx >> 3, h = idx & 7;
    int s = src[e], d = dst[e];
    const unsigned short* kp = K + (size_t)s * 256 + h * 32;
    const unsigned short* qp = Q + (size_t)d * 256 + h * 32;
    float dot = 0.f;
#pragma unroll
    for (int j = 0; j < 32; ++j) dot += bf2f(kp[j]) * bf2f(qp[j]);
    float sc = dot * SCALE_QK;
    score[idx] = sc;
    atomicMax(&m_ord[d * 8 + h], ford(sc));   // ford(finite) > 0 == init
}

__global__ __launch_bounds__(256) void score_pass2(
    const int* __restrict__ dst, float* __restrict__ score,
    const unsigned* __restrict__ m_ord, float* __restrict__ denom)
{
    int idx = blockIdx.x * 256 + threadIdx.x;
    if (idx >= EE * 8) return;
    int e = idx >> 3, h = idx & 7;
    int d = dst[e];
    float mv = ford_inv(m_ord[d * 8 + h]);
    float a = __expf(score[idx] - mv);
    score[idx] = a;
    atomicAdd(&denom[d * 8 + h], a);
}

__global__ __launch_bounds__(256) void v_pass3(
    const unsigned short* __restrict__ V, const int* __restrict__ src,
    const int* __restrict__ dst, const float* __restrict__ score,
    float* __restrict__ acc)
{
    int e = blockIdx.x, t = threadIdx.x;
    float a = score[e * 8 + (t >> 5)];
    int s = src[e], d = dst[e];
    atomicAdd(&acc[(size_t)d * 256 + t], bf2f(V[(size_t)s * 256 + t]) * a);
}

__global__ __launch_bounds__(256) void finalize_gm(
    const float* __restrict__ acc, const float* __restrict__ denom,
    unsigned short* __restrict__ gm, int* __restrict__ flag)
{
    int d = blockIdx.x, t = threadIdx.x;
    float den = denom[d * 8 + (t >> 5)];
    float r = (den > 0.f) ? acc[(size_t)d * 256 + t] / den : 0.f;
    gm[(size_t)d * 256 + t] = f2bf(r);
    if (t == 0) flag[d] = (den > 0.f) ? 1 : 0;
}

// fp32 LN store
__device__ __forceinline__ void block_ln_store(
    float x, const float* __restrict__ g, const float* __restrict__ b,
    float* __restrict__ out, int d, int t)
{
    __shared__ float rbuf[8];
    float s1 = x, s2 = x * x;
#pragma unroll
    for (int o = 1; o < 64; o <<= 1) { s1 += __shfl_xor(s1, o); s2 += __shfl_xor(s2, o); }
    int lane = t & 63, wv = t >> 6;
    if (lane == 0) { rbuf[wv] = s1; rbuf[4 + wv] = s2; }
    __syncthreads();
    float a0 = rbuf[0] + rbuf[1] + rbuf[2] + rbuf[3];
    float b0 = rbuf[4] + rbuf[5] + rbuf[6] + rbuf[7];
    float mu = a0 * (1.f / 256.f);
    float var = fmaxf(b0 * (1.f / 256.f) - mu * mu, 0.f);
    float y = (x - mu) * rsqrtf(var + LNEPS) * g[t] + b[t];
    out[(size_t)d * 256 + t] = y;
}

__global__ __launch_bounds__(256) void finalize_ln(
    const float* __restrict__ acc, const float* __restrict__ denom,
    const float* __restrict__ feat, const float* __restrict__ g,
    const float* __restrict__ b, float* __restrict__ out)
{
    int d = blockIdx.x, t = threadIdx.x;
    float den = denom[d * 8 + (t >> 5)];
    float msg = (den > 0.f) ? acc[(size_t)d * 256 + t] / den : 0.f;
    float x = feat[(size_t)d * 256 + t] + gelu_exact(msg);
    block_ln_store(x, g, b, out, d, t);
}

__global__ __launch_bounds__(256) void gene_fusion_kernel(
    const float* __restrict__ gene_feat, const unsigned short* __restrict__ gm_d,
    const unsigned short* __restrict__ gm_s, const float* __restrict__ e1,
    const float* __restrict__ e2, const int* __restrict__ flag_d,
    const int* __restrict__ flag_s, const float* __restrict__ g,
    const float* __restrict__ b, float* __restrict__ out)
{
    int d = blockIdx.x, t = threadIdx.x;
    float g1 = bf2f(gm_d[(size_t)d * 256 + t]);
    float g2 = bf2f(gm_s[(size_t)d * 256 + t]);
    bool hd = flag_d[d] != 0, hs = flag_s[d] != 0;
    float msg;
    if (hd && hs) {
        float a = e1[d], bb = e2[d];
        float mm = fmaxf(a, bb);   // softmax([e1+bv,e2+bv]) == softmax([e1,e2])
        float wa = __expf(a - mm), wb = __expf(bb - mm);
        msg = (wa * g1 + wb * g2) / (wa + wb);
    } else if (hd) msg = g1;
    else if (hs) msg = g2;
    else msg = 0.f;
    float x = gene_feat[(size_t)d * 256 + t] + gelu_exact(msg);
    block_ln_store(x, g, b, out, d, t);
}

// ---------------------------------------------------------------------------
extern "C" void kernel_launch(void* const* d_in, const int* in_sizes, int n_in,
                              void* d_out, int out_size, void* d_ws, size_t ws_size,
                              hipStream_t stream)
{
    float* out_f32 = (float*)d_out;

    const float* gene_feat    = (const float*)d_in[0];
    const float* drug_feat    = (const float*)d_in[1];
    const float* disease_feat = (const float*)d_in[2];
    const float* dg_Wq = (const float*)d_in[3];
    const float* dg_bq = (const float*)d_in[4];
    const float* dg_Wk = (const float*)d_in[5];
    const float* dg_bk = (const float*)d_in[6];
    const float* dg_Wv = (const float*)d_in[7];
    const float* dg_bv = (const float*)d_in[8];
    const float* disg_Wq = (const float*)d_in[9];
    const float* disg_bq = (const float*)d_in[10];
    const float* disg_Wk = (const float*)d_in[11];
    const float* disg_bk = (const float*)d_in[12];
    const float* disg_Wv = (const float*)d_in[13];
    const float* disg_bv = (const float*)d_in[14];
    const float* gd_Wq = (const float*)d_in[15];
    const float* gd_bq = (const float*)d_in[16];
    const float* gd_Wk = (const float*)d_in[17];
    const float* gd_bk = (const float*)d_in[18];
    const float* gd_Wv = (const float*)d_in[19];
    const float* gd_bv = (const float*)d_in[20];
    const float* gdis_Wq = (const float*)d_in[21];
    const float* gdis_bq = (const float*)d_in[22];
    const float* gdis_Wk = (const float*)d_in[23];
    const float* gdis_bk = (const float*)d_in[24];
    const float* gdis_Wv = (const float*)d_in[25];
    const float* gdis_bv = (const float*)d_in[26];
    const float* f_W1 = (const float*)d_in[27];
    const float* f_b1 = (const float*)d_in[28];
    const float* f_W2 = (const float*)d_in[29];
    const float* f_b2 = (const float*)d_in[30];
    const float* f_v  = (const float*)d_in[31];
    const float* ln1_g = (const float*)d_in[33];
    const float* ln1_b = (const float*)d_in[34];
    const float* ln2_g = (const float*)d_in[35];
    const float* ln2_b = (const float*)d_in[36];
    const int* dg_src   = (const int*)d_in[37];
    const int* dg_dst   = (const int*)d_in[38];
    const int* disg_src = (const int*)d_in[39];
    const int* disg_dst = (const int*)d_in[40];
    const int* gd_src   = (const int*)d_in[41];
    const int* gd_dst   = (const int*)d_in[42];
    const int* gdis_src = (const int*)d_in[43];
    const int* gdis_dst = (const int*)d_in[44];

    // ---- workspace (~62.5 MB) ----
    char* ws = (char*)d_ws;
    size_t off = 0;
    auto alloc = [&](size_t bytes) -> char* {
        char* p = ws + off;
        off += (bytes + 511) & ~(size_t)511;
        return p;
    };
    float*    e1     = (float*)alloc(NG * 4);
    float*    e2     = (float*)alloc(NG * 4);
    int*      flag_d = (int*)alloc(NG * 4);
    int*      flag_s = (int*)alloc(NG * 4);
    unsigned* m_ord  = (unsigned*)alloc(NG * 8 * 4);
    float*    denom  = (float*)alloc(NG * 8 * 4);
    float*    score  = (float*)alloc((size_t)EE * 8 * 4);
    unsigned short* Vb   = (unsigned short*)alloc((size_t)NG * 256 * 2);
    unsigned short* gm_d = (unsigned short*)alloc((size_t)NG * 256 * 2);
    unsigned short* gm_s = (unsigned short*)alloc((size_t)NG * 256 * 2);
    unsigned short* Qb   = (unsigned short*)alloc((size_t)NG * 256 * 2);  // contiguous
    unsigned short* Kb   = (unsigned short*)alloc((size_t)NG * 256 * 2);  // with Qb
    float* acc = (float*)Qb;   // fp32 acc [NG,256] aliases Qb+Kb (dead by pass3)
    size_t need = off;

    float* out_drug = out_f32;                         // [8000, 256]
    float* out_dis  = out_drug + (size_t)ND * 256;     // [8000, 256]
    float* out_gene = out_dis + (size_t)NS * 256;      // [20000, 256]

    if (ws_size < need) {   // sentinel: 1000.0f
        fillf_kernel<<<(out_size + 255) / 256, 256, 0, stream>>>(out_f32, out_size, 1000.0f);
        return;
    }

    auto zero = [&](void* p, size_t n_ints) {
        zero_kernel<<<((int)n_ints + 255) / 256, 256, 0, stream>>>((int*)p, (int)n_ints);
    };
    auto gemmF = [&](const float* A, const float* W, const float* bias,
                     unsigned short* C, int M) {
        gemm_simple<0, 0><<<(M + 15) / 16, 256, 0, stream>>>(A, W, bias, C, nullptr, nullptr, M);
    };
    const int EG = (EE * 8 + 255) / 256;
    auto run_attn = [&](const int* src, const int* dst, int ndst) {
        zero(m_ord, (size_t)ndst * 8);
        zero(denom, (size_t)ndst * 8);
        score_pass1<<<EG, 256, 0, stream>>>(Qb, Kb, src, dst, score, m_ord);
        score_pass2<<<EG, 256, 0, stream>>>(dst, score, m_ord, denom);
        zero(acc, (size_t)ndst * 256);   // clobbers Qb/Kb (dead after pass1)
        v_pass3<<<EE, 256, 0, stream>>>(Vb, src, dst, score, acc);
    };

    zero(e1, NG);
    zero(e2, NG);

    // ---- stage 1: drug->gene ----
    gemmF(gene_feat, dg_Wq, dg_bq, Qb, NG);
    gemmF(drug_feat, dg_Wk, dg_bk, Kb, ND);
    gemmF(drug_feat, dg_Wv, dg_bv, Vb, ND);
    run_attn(dg_src, dg_dst, NG);
    finalize_gm<<<NG, 256, 0, stream>>>(acc, denom, gm_d, flag_d);

    // ---- stage 1: disease->gene ----
    gemmF(gene_feat, disg_Wq, disg_bq, Qb, NG);
    gemmF(disease_feat, disg_Wk, disg_bk, Kb, NS);
    gemmF(disease_feat, disg_Wv, disg_bv, Vb, NS);
    run_attn(disg_src, disg_dst, NG);
    finalize_gm<<<NG, 256, 0, stream>>>(acc, denom, gm_s, flag_s);

    // ---- Bahdanau fusion + LN1 -> gene_out (fp32, last output chunk) ----
    gemm_simple<1, 1><<<(NG + 15) / 16, 256, 0, stream>>>(gm_d, f_W1, f_b1, nullptr, f_v, e1, NG);
    gemm_simple<1, 1><<<(NG + 15) / 16, 256, 0, stream>>>(gm_s, f_W2, f_b2, nullptr, f_v, e2, NG);
    gene_fusion_kernel<<<NG, 256, 0, stream>>>(gene_feat, gm_d, gm_s, e1, e2,
                                               flag_d, flag_s, ln1_g, ln1_b, out_gene);

    // ---- stage 2: gene->drug (K/V from fp32 gene_out) ----
    gemmF(drug_feat, gd_Wq, gd_bq, Qb, ND);
    gemmF(out_gene, gd_Wk, gd_bk, Kb, NG);
    gemmF(out_gene, gd_Wv, gd_bv, Vb, NG);
    run_attn(gd_src, gd_dst, ND);
    finalize_ln<<<ND, 256, 0, stream>>>(acc, denom, drug_feat, ln2_g, ln2_b, out_drug);

    // ---- stage 2: gene->disease ----
    gemmF(disease_feat, gdis_Wq, gdis_bq, Qb, NS);
    gemmF(out_gene, gdis_Wk, gdis_bk, Kb, NG);
    gemmF(out_gene, gdis_Wv, gdis_bv, Vb, NG);
    run_attn(gdis_src, gdis_dst, NS);
    finalize_ln<<<NS, 256, 0, stream>>>(acc, denom, disease_feat, ln2_g, ln2_b, out_dis);
}

// Round 10
// 1010.114 us; speedup vs baseline: 2.3139x; 2.3139x over previous
//
#include <hip/hip_runtime.h>

#define NG 20000
#define ND 8000
#define NS 8000
#define EE 300000
#define DIM 256
#define SCALE_QK 0.17677669529663687f  // 1/sqrt(32)
#define LNEPS 1e-5f

typedef __attribute__((ext_vector_type(4))) float floatx4;
typedef __attribute__((ext_vector_type(8))) short shortx8;

__device__ __forceinline__ float bf2f(unsigned short u) {
    union { unsigned u; float f; } c; c.u = ((unsigned)u) << 16; return c.f;
}
__device__ __forceinline__ unsigned short f2bf(float f) {
    union { float f; unsigned u; } c; c.f = f;
    return (unsigned short)((c.u + 0x7fffu + ((c.u >> 16) & 1u)) >> 16);
}
__device__ __forceinline__ float gelu_exact(float v) {
    return 0.5f * v * (1.0f + erff(v * 0.70710678118654752f));
}

// ---------------------------------------------------------------------------
// MFMA GEMM: C[M,256] = A[M,256] @ W[256,256]^T + bias
// A: fp32 (ABF=0) or bf16 scratch (ABF=1); W,bias fp32; C bf16 scratch.
// MODE 0: store bf16 C.  MODE 1: Bahdanau epilogue e[m] += sum_n v[n]*tanh(C+b)
// Tile 128m x 64n, BK=32, 256 threads (4 waves; wave -> 32 m-rows).
// mfma_f32_16x16x32_bf16 layouts (HW-verified, guide §3):
//   A/B frag: 8 contiguous k of row (lane&15), quad=lane>>4 picks k-octet
//   C/D: col = lane&15, row = quad*4 + reg
// ---------------------------------------------------------------------------
template <int MODE, int ABF>
__global__ __launch_bounds__(256, 2) void gemm_nt(
    const void* __restrict__ Ap, const float* __restrict__ W,
    const float* __restrict__ bias, unsigned short* __restrict__ C,
    const float* __restrict__ vvec, float* __restrict__ evec, int M)
{
    __shared__ unsigned short As[128][40];  // 40 shorts = 80 B rows (16B-aligned)
    __shared__ unsigned short Bs[64][40];
    const int tid = threadIdx.x;
    const int lane = tid & 63, wv = tid >> 6;
    const int quad = lane >> 4, l16 = lane & 15;
    const int m0 = blockIdx.x * 128;
    const int n0 = blockIdx.y * 64;

    floatx4 acc[2][4];
#pragma unroll
    for (int i = 0; i < 2; ++i)
#pragma unroll
        for (int j = 0; j < 4; ++j) acc[i][j] = (floatx4){0.f, 0.f, 0.f, 0.f};

    const int sr = tid >> 2;         // 0..63
    const int sc = (tid & 3) * 8;    // 0,8,16,24

    for (int k0 = 0; k0 < 256; k0 += 32) {
        __syncthreads();
        {   // B tile: row = output col n0+sr; fp32 -> bf16
            const float* wp = W + (size_t)(n0 + sr) * 256 + k0 + sc;
            float4 f0 = *(const float4*)(wp);
            float4 f1 = *(const float4*)(wp + 4);
            unsigned short tmp[8] = {f2bf(f0.x), f2bf(f0.y), f2bf(f0.z), f2bf(f0.w),
                                     f2bf(f1.x), f2bf(f1.y), f2bf(f1.z), f2bf(f1.w)};
            *(int4*)(&Bs[sr][sc]) = *(const int4*)tmp;
        }
#pragma unroll
        for (int rr = 0; rr < 2; ++rr) {  // A tile: 128 rows
            int row = sr + rr * 64;
            int gm = m0 + row;
            if (ABF) {
                int4 av = make_int4(0, 0, 0, 0);
                if (gm < M)
                    av = *(const int4*)((const unsigned short*)Ap + (size_t)gm * 256 + k0 + sc);
                *(int4*)(&As[row][sc]) = av;
            } else {
                float4 f0 = make_float4(0.f, 0.f, 0.f, 0.f), f1 = f0;
                if (gm < M) {
                    const float* ap = (const float*)Ap + (size_t)gm * 256 + k0 + sc;
                    f0 = *(const float4*)(ap);
                    f1 = *(const float4*)(ap + 4);
                }
                unsigned short tmp[8] = {f2bf(f0.x), f2bf(f0.y), f2bf(f0.z), f2bf(f0.w),
                                         f2bf(f1.x), f2bf(f1.y), f2bf(f1.z), f2bf(f1.w)};
                *(int4*)(&As[row][sc]) = *(const int4*)tmp;
            }
        }
        __syncthreads();
        shortx8 af[2], bfr[4];
#pragma unroll
        for (int mf = 0; mf < 2; ++mf)
            af[mf] = *(const shortx8*)(&As[wv * 32 + mf * 16 + l16][quad * 8]);
#pragma unroll
        for (int nf = 0; nf < 4; ++nf)
            bfr[nf] = *(const shortx8*)(&Bs[nf * 16 + l16][quad * 8]);
#pragma unroll
        for (int mf = 0; mf < 2; ++mf)
#pragma unroll
            for (int nf = 0; nf < 4; ++nf)
                acc[mf][nf] = __builtin_amdgcn_mfma_f32_16x16x32_bf16(
                    af[mf], bfr[nf], acc[mf][nf], 0, 0, 0);
    }

    if (MODE == 0) {
#pragma unroll
        for (int mf = 0; mf < 2; ++mf)
#pragma unroll
            for (int r = 0; r < 4; ++r) {
                int m = m0 + wv * 32 + mf * 16 + quad * 4 + r;
                if (m < M) {
#pragma unroll
                    for (int nf = 0; nf < 4; ++nf) {
                        int n = n0 + nf * 16 + l16;
                        C[(size_t)m * 256 + n] = f2bf(acc[mf][nf][r] + bias[n]);
                    }
                }
            }
    } else {
        float p[2][4] = {};
#pragma unroll
        for (int mf = 0; mf < 2; ++mf)
#pragma unroll
            for (int nf = 0; nf < 4; ++nf) {
                int n = n0 + nf * 16 + l16;
                float vn = vvec[n];
                float bn = bias[n];
#pragma unroll
                for (int r = 0; r < 4; ++r)
                    p[mf][r] += vn * tanhf(acc[mf][nf][r] + bn);
            }
#pragma unroll
        for (int mf = 0; mf < 2; ++mf)
#pragma unroll
            for (int r = 0; r < 4; ++r) {
                float s = p[mf][r];
                s += __shfl_xor(s, 1); s += __shfl_xor(s, 2);
                s += __shfl_xor(s, 4); s += __shfl_xor(s, 8);
                if (l16 == 0) {
                    int m = m0 + wv * 32 + mf * 16 + quad * 4 + r;
                    if (m < M) atomicAdd(&evec[m], s);
                }
            }
    }
}

// ---------------------------------------------------------------------------
// Utility + CSR build
// ---------------------------------------------------------------------------
__global__ void zero_kernel(int* __restrict__ p, int n) {
    int i = blockIdx.x * blockDim.x + threadIdx.x;
    if (i < n) p[i] = 0;
}
__global__ void fillf_kernel(float* __restrict__ p, int n, float v) {
    int i = blockIdx.x * blockDim.x + threadIdx.x;
    if (i < n) p[i] = v;
}
__global__ void count_kernel(const int* __restrict__ dst, int* __restrict__ cnt, int n) {
    int i = blockIdx.x * blockDim.x + threadIdx.x;
    if (i < n) atomicAdd(&cnt[dst[i]], 1);
}
__global__ void scatter_kernel(const int* __restrict__ src, const int* __restrict__ dst,
                               const int* __restrict__ offs, int* __restrict__ cur,
                               int* __restrict__ srcs, int n) {
    int i = blockIdx.x * blockDim.x + threadIdx.x;
    if (i < n) {
        int d = dst[i];
        int pos = offs[d] + atomicAdd(&cur[d], 1);
        srcs[pos] = src[i];
    }
}
__device__ void block_exscan(const int* cnt, int* offs, int n) {
    __shared__ int wsum[4];
    int t = threadIdx.x, lane = t & 63, wv = t >> 6;
    int carry = 0;
    for (int base = 0; base < n; base += 256) {
        int i = base + t;
        int v = (i < n) ? cnt[i] : 0;
        int x = v;
#pragma unroll
        for (int o = 1; o < 64; o <<= 1) {
            int u = __shfl_up(x, o);
            if (lane >= o) x += u;
        }
        if (lane == 63) wsum[wv] = x;
        __syncthreads();
        int woff = 0;
        for (int w = 0; w < wv; ++w) woff += wsum[w];
        int total = wsum[0] + wsum[1] + wsum[2] + wsum[3];
        if (i < n) offs[i] = carry + woff + x - v;   // exclusive prefix
        carry += total;
        __syncthreads();
    }
}
__global__ void scan4_kernel(const int* c0, int* o0, int n0, const int* c1, int* o1, int n1,
                             const int* c2, int* o2, int n2, const int* c3, int* o3, int n3) {
    if (blockIdx.x == 0) block_exscan(c0, o0, n0);
    else if (blockIdx.x == 1) block_exscan(c1, o1, n1);
    else if (blockIdx.x == 2) block_exscan(c2, o2, n2);
    else block_exscan(c3, o3, n3);
}

// ---------------------------------------------------------------------------
// Fused CSR aggregation: one block per dst node; thread t owns feature t,
// head = t>>5 (32-lane group in-wave). Per edge: dot via shfl_xor butterfly,
// online-softmax rescale, V accumulate. Atomic-free.
// ---------------------------------------------------------------------------
__device__ __forceinline__ void online_attn(
    const unsigned short* __restrict__ Q, const unsigned short* __restrict__ K,
    const unsigned short* __restrict__ V, const int* __restrict__ offs,
    const int* __restrict__ cnt, const int* __restrict__ srcs,
    int d, int t, float& outv, float& outl)
{
    float q = bf2f(Q[(size_t)d * 256 + t]);
    int beg = offs[d];
    int num = cnt[d];
    float m = -INFINITY, l = 0.f, acc = 0.f;
    for (int i = 0; i < num; ++i) {
        int s = srcs[beg + i];
        float p = bf2f(K[(size_t)s * 256 + t]) * q;
        p += __shfl_xor(p, 1); p += __shfl_xor(p, 2); p += __shfl_xor(p, 4);
        p += __shfl_xor(p, 8); p += __shfl_xor(p, 16);
        float sc = p * SCALE_QK;
        float mn = fmaxf(m, sc);
        float eo = __expf(m - mn);   // first iter: exp(-inf)=0
        float en = __expf(sc - mn);
        float vv = bf2f(V[(size_t)s * 256 + t]);
        acc = acc * eo + en * vv;
        l = l * eo + en;
        m = mn;
    }
    outv = acc; outl = l;
}

__device__ __forceinline__ void block_ln_store(
    float x, const float* __restrict__ g, const float* __restrict__ b,
    float* __restrict__ out, int d, int t)
{
    __shared__ float rbuf[8];
    float s1 = x, s2 = x * x;
#pragma unroll
    for (int o = 1; o < 64; o <<= 1) { s1 += __shfl_xor(s1, o); s2 += __shfl_xor(s2, o); }
    int lane = t & 63, wv = t >> 6;
    if (lane == 0) { rbuf[wv] = s1; rbuf[4 + wv] = s2; }
    __syncthreads();
    float a0 = rbuf[0] + rbuf[1] + rbuf[2] + rbuf[3];
    float b0 = rbuf[4] + rbuf[5] + rbuf[6] + rbuf[7];
    float mu = a0 * (1.f / 256.f);
    float var = fmaxf(b0 * (1.f / 256.f) - mu * mu, 0.f);
    float y = (x - mu) * rsqrtf(var + LNEPS) * g[t] + b[t];
    out[(size_t)d * 256 + t] = y;
}

__global__ __launch_bounds__(256) void agg_gm_kernel(
    const unsigned short* __restrict__ Q, const unsigned short* __restrict__ K,
    const unsigned short* __restrict__ V, const int* __restrict__ offs,
    const int* __restrict__ cnt, const int* __restrict__ srcs,
    unsigned short* __restrict__ gm)
{
    int d = blockIdx.x, t = threadIdx.x;
    float acc, l;
    online_attn(Q, K, V, offs, cnt, srcs, d, t, acc, l);
    gm[(size_t)d * 256 + t] = f2bf((l > 0.f) ? acc / l : 0.f);
}

__global__ __launch_bounds__(256) void agg_ln_kernel(
    const unsigned short* __restrict__ Q, const unsigned short* __restrict__ K,
    const unsigned short* __restrict__ V, const int* __restrict__ offs,
    const int* __restrict__ cnt, const int* __restrict__ srcs,
    const float* __restrict__ feat, const float* __restrict__ g,
    const float* __restrict__ b, float* __restrict__ out)
{
    int d = blockIdx.x, t = threadIdx.x;
    float acc, l;
    online_attn(Q, K, V, offs, cnt, srcs, d, t, acc, l);
    float msg = (l > 0.f) ? acc / l : 0.f;
    float x = feat[(size_t)d * 256 + t] + gelu_exact(msg);
    block_ln_store(x, g, b, out, d, t);
}

__global__ __launch_bounds__(256) void gene_fusion_kernel(
    const float* __restrict__ gene_feat, const unsigned short* __restrict__ gm_d,
    const unsigned short* __restrict__ gm_s, const float* __restrict__ e1,
    const float* __restrict__ e2, const int* __restrict__ cnt_d,
    const int* __restrict__ cnt_s, const float* __restrict__ g,
    const float* __restrict__ b, float* __restrict__ out)
{
    int d = blockIdx.x, t = threadIdx.x;
    float g1 = bf2f(gm_d[(size_t)d * 256 + t]);
    float g2 = bf2f(gm_s[(size_t)d * 256 + t]);
    bool hd = cnt_d[d] > 0, hs = cnt_s[d] > 0;
    float msg;
    if (hd && hs) {
        float a = e1[d], bb = e2[d];
        float mm = fmaxf(a, bb);   // softmax([e1+bv,e2+bv]) == softmax([e1,e2])
        float wa = __expf(a - mm), wb = __expf(bb - mm);
        msg = (wa * g1 + wb * g2) / (wa + wb);
    } else if (hd) msg = g1;
    else if (hs) msg = g2;
    else msg = 0.f;
    float x = gene_feat[(size_t)d * 256 + t] + gelu_exact(msg);
    block_ln_store(x, g, b, out, d, t);
}

// ---------------------------------------------------------------------------
extern "C" void kernel_launch(void* const* d_in, const int* in_sizes, int n_in,
                              void* d_out, int out_size, void* d_ws, size_t ws_size,
                              hipStream_t stream)
{
    float* out_f32 = (float*)d_out;

    const float* gene_feat    = (const float*)d_in[0];
    const float* drug_feat    = (const float*)d_in[1];
    const float* disease_feat = (const float*)d_in[2];
    const float* dg_Wq = (const float*)d_in[3];
    const float* dg_bq = (const float*)d_in[4];
    const float* dg_Wk = (const float*)d_in[5];
    const float* dg_bk = (const float*)d_in[6];
    const float* dg_Wv = (const float*)d_in[7];
    const float* dg_bv = (const float*)d_in[8];
    const float* disg_Wq = (const float*)d_in[9];
    const float* disg_bq = (const float*)d_in[10];
    const float* disg_Wk = (const float*)d_in[11];
    const float* disg_bk = (const float*)d_in[12];
    const float* disg_Wv = (const float*)d_in[13];
    const float* disg_bv = (const float*)d_in[14];
    const float* gd_Wq = (const float*)d_in[15];
    const float* gd_bq = (const float*)d_in[16];
    const float* gd_Wk = (const float*)d_in[17];
    const float* gd_bk = (const float*)d_in[18];
    const float* gd_Wv = (const float*)d_in[19];
    const float* gd_bv = (const float*)d_in[20];
    const float* gdis_Wq = (const float*)d_in[21];
    const float* gdis_bq = (const float*)d_in[22];
    const float* gdis_Wk = (const float*)d_in[23];
    const float* gdis_bk = (const float*)d_in[24];
    const float* gdis_Wv = (const float*)d_in[25];
    const float* gdis_bv = (const float*)d_in[26];
    const float* f_W1 = (const float*)d_in[27];
    const float* f_b1 = (const float*)d_in[28];
    const float* f_W2 = (const float*)d_in[29];
    const float* f_b2 = (const float*)d_in[30];
    const float* f_v  = (const float*)d_in[31];
    const float* ln1_g = (const float*)d_in[33];
    const float* ln1_b = (const float*)d_in[34];
    const float* ln2_g = (const float*)d_in[35];
    const float* ln2_b = (const float*)d_in[36];
    const int* dg_src   = (const int*)d_in[37];
    const int* dg_dst   = (const int*)d_in[38];
    const int* disg_src = (const int*)d_in[39];
    const int* disg_dst = (const int*)d_in[40];
    const int* gd_src   = (const int*)d_in[41];
    const int* gd_dst   = (const int*)d_in[42];
    const int* gdis_src = (const int*)d_in[43];
    const int* gdis_dst = (const int*)d_in[44];

    // ---- workspace (~57 MB) ----
    char* ws = (char*)d_ws;
    size_t off = 0;
    auto alloc = [&](size_t bytes) -> char* {
        char* p = ws + off;
        off += (bytes + 511) & ~(size_t)511;
        return p;
    };
    // zero region start
    int* cnt_dg   = (int*)alloc(NG * 4);
    int* cnt_disg = (int*)alloc(NG * 4);
    int* cnt_gd   = (int*)alloc(ND * 4);
    int* cnt_gdis = (int*)alloc(NS * 4);
    int* cur_dg   = (int*)alloc(NG * 4);
    int* cur_disg = (int*)alloc(NG * 4);
    int* cur_gd   = (int*)alloc(ND * 4);
    int* cur_gdis = (int*)alloc(NS * 4);
    float* e1 = (float*)alloc(NG * 4);
    float* e2 = (float*)alloc(NG * 4);
    size_t zero_len = off;   // bytes to zero each call
    int* offs_dg   = (int*)alloc(NG * 4);
    int* offs_disg = (int*)alloc(NG * 4);
    int* offs_gd   = (int*)alloc(ND * 4);
    int* offs_gdis = (int*)alloc(NS * 4);
    int* srcs_dg   = (int*)alloc((size_t)EE * 4);
    int* srcs_disg = (int*)alloc((size_t)EE * 4);
    int* srcs_gd   = (int*)alloc((size_t)EE * 4);
    int* srcs_gdis = (int*)alloc((size_t)EE * 4);
    unsigned short* Qb   = (unsigned short*)alloc((size_t)NG * 256 * 2);
    unsigned short* Kb   = (unsigned short*)alloc((size_t)NG * 256 * 2);
    unsigned short* Vb   = (unsigned short*)alloc((size_t)NG * 256 * 2);
    unsigned short* gm_d = (unsigned short*)alloc((size_t)NG * 256 * 2);
    unsigned short* gm_s = (unsigned short*)alloc((size_t)NG * 256 * 2);
    size_t need = off;

    float* out_drug = out_f32;                       // [8000, 256]
    float* out_dis  = out_drug + (size_t)ND * 256;   // [8000, 256]
    float* out_gene = out_dis + (size_t)NS * 256;    // [20000, 256]

    if (ws_size < need) {   // sentinel: 1000.0f
        fillf_kernel<<<(out_size + 255) / 256, 256, 0, stream>>>(out_f32, out_size, 1000.0f);
        return;
    }

    zero_kernel<<<((int)(zero_len / 4) + 255) / 256, 256, 0, stream>>>(
        (int*)d_ws, (int)(zero_len / 4));

    // ---- CSR build for all 4 graphs ----
    const int EB = (EE + 255) / 256;
    count_kernel<<<EB, 256, 0, stream>>>(dg_dst, cnt_dg, EE);
    count_kernel<<<EB, 256, 0, stream>>>(disg_dst, cnt_disg, EE);
    count_kernel<<<EB, 256, 0, stream>>>(gd_dst, cnt_gd, EE);
    count_kernel<<<EB, 256, 0, stream>>>(gdis_dst, cnt_gdis, EE);
    scan4_kernel<<<4, 256, 0, stream>>>(cnt_dg, offs_dg, NG, cnt_disg, offs_disg, NG,
                                        cnt_gd, offs_gd, ND, cnt_gdis, offs_gdis, NS);
    scatter_kernel<<<EB, 256, 0, stream>>>(dg_src, dg_dst, offs_dg, cur_dg, srcs_dg, EE);
    scatter_kernel<<<EB, 256, 0, stream>>>(disg_src, disg_dst, offs_disg, cur_disg, srcs_disg, EE);
    scatter_kernel<<<EB, 256, 0, stream>>>(gd_src, gd_dst, offs_gd, cur_gd, srcs_gd, EE);
    scatter_kernel<<<EB, 256, 0, stream>>>(gdis_src, gdis_dst, offs_gdis, cur_gdis, srcs_gdis, EE);

    auto gemmF = [&](const float* A, const float* W, const float* bias,
                     unsigned short* C, int M) {
        dim3 g((M + 127) / 128, 4);
        gemm_nt<0, 0><<<g, 256, 0, stream>>>(A, W, bias, C, nullptr, nullptr, M);
    };

    // ---- stage 1: drug->gene ----
    gemmF(gene_feat, dg_Wq, dg_bq, Qb, NG);
    gemmF(drug_feat, dg_Wk, dg_bk, Kb, ND);
    gemmF(drug_feat, dg_Wv, dg_bv, Vb, ND);
    agg_gm_kernel<<<NG, 256, 0, stream>>>(Qb, Kb, Vb, offs_dg, cnt_dg, srcs_dg, gm_d);

    // ---- stage 1: disease->gene ----
    gemmF(gene_feat, disg_Wq, disg_bq, Qb, NG);
    gemmF(disease_feat, disg_Wk, disg_bk, Kb, NS);
    gemmF(disease_feat, disg_Wv, disg_bv, Vb, NS);
    agg_gm_kernel<<<NG, 256, 0, stream>>>(Qb, Kb, Vb, offs_disg, cnt_disg, srcs_disg, gm_s);

    // ---- Bahdanau fusion + LN1 -> gene_out (fp32) ----
    {
        dim3 gb((NG + 127) / 128, 4);
        gemm_nt<1, 1><<<gb, 256, 0, stream>>>(gm_d, f_W1, f_b1, nullptr, f_v, e1, NG);
        gemm_nt<1, 1><<<gb, 256, 0, stream>>>(gm_s, f_W2, f_b2, nullptr, f_v, e2, NG);
    }
    gene_fusion_kernel<<<NG, 256, 0, stream>>>(gene_feat, gm_d, gm_s, e1, e2,
                                               cnt_dg, cnt_disg, ln1_g, ln1_b, out_gene);

    // ---- stage 2: gene->drug ----
    gemmF(drug_feat, gd_Wq, gd_bq, Qb, ND);
    gemmF(out_gene, gd_Wk, gd_bk, Kb, NG);
    gemmF(out_gene, gd_Wv, gd_bv, Vb, NG);
    agg_ln_kernel<<<ND, 256, 0, stream>>>(Qb, Kb, Vb, offs_gd, cnt_gd, srcs_gd,
                                          drug_feat, ln2_g, ln2_b, out_drug);

    // ---- stage 2: gene->disease ----
    gemmF(disease_feat, gdis_Wq, gdis_bq, Qb, NS);
    gemmF(out_gene, gdis_Wk, gdis_bk, Kb, NG);
    gemmF(out_gene, gdis_Wv, gdis_bv, Vb, NG);
    agg_ln_kernel<<<NS, 256, 0, stream>>>(Qb, Kb, Vb, offs_gdis, cnt_gdis, srcs_gdis,
                                          disease_feat, ln2_g, ln2_b, out_dis);
}